// Round 3
// baseline (281.981 us; speedup 1.0000x reference)
//
#include <hip/hip_runtime.h>

#define VOCAB 128
#define EMB   8
#define HID   32
#define BATCH 512
#define SEQ   512
#define G4    128   // 4*HID
#define KB    8     // recurrence steps per batch-phase

// ---------------------------------------------------------------------------
// Kernel 1: proj[v][r] = dot(emb[v], w_ih[r]) + b_ih[r] + b_hh[r]
// ---------------------------------------------------------------------------
__global__ void build_proj(const float* __restrict__ emb,
                           const float* __restrict__ w_ih,
                           const float* __restrict__ b_ih,
                           const float* __restrict__ b_hh,
                           float* __restrict__ proj) {
    int idx = blockIdx.x * blockDim.x + threadIdx.x;   // 0 .. 16383
    int v = idx >> 7;
    int r = idx & 127;
    float acc = b_ih[r] + b_hh[r];
#pragma unroll
    for (int e = 0; e < EMB; ++e)
        acc += emb[v * EMB + e] * w_ih[r * EMB + e];
    proj[v * G4 + r] = acc;
}

// ---------------------------------------------------------------------------
// Kernel 2: LSTM recurrence. One wave per batch sequence.
// Lane l owns gate rows l and l+64. h broadcast via v_readlane.
// Weights pinned in VGPRs via opaque asm (blocks rematerialization).
// xp loads batched 8 steps deep, fenced with sched_barrier so latency
// hides under the previous batch's compute.
// ---------------------------------------------------------------------------
__device__ __forceinline__ float sigmoid_fast(float x) {
    return 1.0f / (1.0f + __expf(-x));
}
__device__ __forceinline__ float tanh_fast(float x) {
    return 1.0f - 2.0f / (__expf(2.0f * x) + 1.0f);
}

__global__ __launch_bounds__(64, 1) void lstm_rec(
    const int*   __restrict__ tokens,   // [B][T]
    const float* __restrict__ w_hh,     // [128][32]
    const float* __restrict__ proj,     // [128][128]
    float*       __restrict__ h_out)    // [B*T][32]
{
    const int b    = blockIdx.x;
    const int lane = threadIdx.x;      // 0..63

    // ---- recurrent weights: 2 gate rows per lane, pinned resident ----
    float w0[HID], w1[HID];
#pragma unroll
    for (int j = 0; j < HID; ++j) {
        w0[j] = w_hh[lane * HID + j];
        w1[j] = w_hh[(lane + 64) * HID + j];
    }
#pragma unroll
    for (int j = 0; j < HID; ++j) {
        asm volatile("" : "+v"(w0[j]), "+v"(w1[j]));   // non-rematerializable
    }

    const int* tok = tokens + b * SEQ;

    // ---- all 512 tokens of this sequence live in lane registers ----
    // lane l holds tok[l*8 .. l*8+7]; broadcast later via v_readlane.
    int tv[KB];
#pragma unroll
    for (int k = 0; k < KB; ++k) tv[k] = tok[lane * KB + k];

    float h = 0.0f, c = 0.0f;
    float* hp = h_out + (size_t)b * SEQ * HID + lane;   // lanes<32 store

    // ---- prime batch 0 xp loads ----
    float cx0[KB], cx1[KB];
#pragma unroll
    for (int k = 0; k < KB; ++k) {
        int tk = __builtin_amdgcn_readlane(tv[k], 0);   // tokens 0..7 in lane 0
        cx0[k] = proj[tk * G4 + lane];
        cx1[k] = proj[tk * G4 + 64 + lane];
    }

    float hsave[KB];

    for (int t0 = 0; t0 < SEQ; t0 += KB) {
        // ---- phase A: issue next-batch xp loads (base wraps to 0 at tail) ----
        const int base = (t0 + KB < SEQ) ? (t0 + KB) : 0;
        float nx0[KB], nx1[KB];
#pragma unroll
        for (int k = 0; k < KB; ++k) {
            // token base+k lives in lane (base+k)/8, slot k (base%8==0)
            int tk = __builtin_amdgcn_readlane(tv[k], (base + k) >> 3);
            nx0[k] = proj[tk * G4 + lane];
            nx1[k] = proj[tk * G4 + 64 + lane];
        }
        __builtin_amdgcn_sched_barrier(0);   // loads may not sink below here

        // ---- phase B: 8 recurrence steps from resident registers ----
#pragma unroll
        for (int k = 0; k < KB; ++k) {
            float s0 = cx0[k], s1 = 0.0f, s2 = 0.0f, s3 = 0.0f;  // row lane
            float u0 = cx1[k], u1 = 0.0f, u2 = 0.0f, u3 = 0.0f;  // row lane+64
            unsigned hb = __float_as_uint(h);
#pragma unroll
            for (int j = 0; j < HID; j += 4) {
                float h0 = __uint_as_float(__builtin_amdgcn_readlane(hb, j));
                float h1 = __uint_as_float(__builtin_amdgcn_readlane(hb, j + 1));
                float h2 = __uint_as_float(__builtin_amdgcn_readlane(hb, j + 2));
                float h3 = __uint_as_float(__builtin_amdgcn_readlane(hb, j + 3));
                s0 = fmaf(h0, w0[j],     s0);
                s1 = fmaf(h1, w0[j + 1], s1);
                s2 = fmaf(h2, w0[j + 2], s2);
                s3 = fmaf(h3, w0[j + 3], s3);
                u0 = fmaf(h0, w1[j],     u0);
                u1 = fmaf(h1, w1[j + 1], u1);
                u2 = fmaf(h2, w1[j + 2], u2);
                u3 = fmaf(h3, w1[j + 3], u3);
            }
            float acc0 = (s0 + s1) + (s2 + s3);  // i (lo lanes) | f (hi lanes)
            float acc1 = (u0 + u1) + (u2 + u3);  // g (lo lanes) | o (hi lanes)

            // broadcast both halves to all lanes via VALU permlane swap
            float iv = acc0, fv = acc0;
            asm("v_permlane32_swap_b32 %0, %1" : "+v"(iv), "+v"(fv));
            float gv = acc1, ov = acc1;
            asm("v_permlane32_swap_b32 %0, %1" : "+v"(gv), "+v"(ov));

            c = sigmoid_fast(fv) * c + sigmoid_fast(iv) * tanh_fast(gv);
            h = sigmoid_fast(ov) * tanh_fast(c);
            hsave[k] = h;
        }

        // ---- flush h stores (one vmcnt high-water per 8 steps) ----
        if (lane < 32) {
#pragma unroll
            for (int k = 0; k < KB; ++k)
                hp[(size_t)(t0 + k) * HID] = hsave[k];
        }

        // ---- rotate next batch into current ----
#pragma unroll
        for (int k = 0; k < KB; ++k) { cx0[k] = nx0[k]; cx1[k] = nx1[k]; }
    }
}

// ---------------------------------------------------------------------------
// Kernel 3: logits[pos][v] = h[pos] . w_out[v] + b_out[v]
// ---------------------------------------------------------------------------
#define POS_PER_WAVE 16

__global__ __launch_bounds__(256) void out_proj(
    const float* __restrict__ h,      // [B*T][32]
    const float* __restrict__ w_out,  // [128][32]
    const float* __restrict__ b_out,  // [128]
    float*       __restrict__ out)    // [B*T][128]
{
    const int gtid = blockIdx.x * blockDim.x + threadIdx.x;
    const int wave = gtid >> 6;
    const int lane = threadIdx.x & 63;

    float wv0[HID], wv1[HID];
#pragma unroll
    for (int j = 0; j < HID; ++j) {
        wv0[j] = w_out[lane * HID + j];
        wv1[j] = w_out[(lane + 64) * HID + j];
    }
    const float bb0 = b_out[lane];
    const float bb1 = b_out[lane + 64];

    int pos0 = wave * POS_PER_WAVE;
    for (int p = 0; p < POS_PER_WAVE; ++p) {
        int pos = __builtin_amdgcn_readfirstlane(pos0 + p);
        const float* hp = h + (size_t)pos * HID;
        float a0 = bb0, a1 = bb1;
#pragma unroll
        for (int j4 = 0; j4 < HID / 4; ++j4) {
            float4 hv = *reinterpret_cast<const float4*>(hp + 4 * j4);
            a0 = fmaf(hv.x, wv0[4 * j4 + 0], a0);
            a1 = fmaf(hv.x, wv1[4 * j4 + 0], a1);
            a0 = fmaf(hv.y, wv0[4 * j4 + 1], a0);
            a1 = fmaf(hv.y, wv1[4 * j4 + 1], a1);
            a0 = fmaf(hv.z, wv0[4 * j4 + 2], a0);
            a1 = fmaf(hv.z, wv1[4 * j4 + 2], a1);
            a0 = fmaf(hv.w, wv0[4 * j4 + 3], a0);
            a1 = fmaf(hv.w, wv1[4 * j4 + 3], a1);
        }
        out[(size_t)pos * VOCAB + lane]      = a0;
        out[(size_t)pos * VOCAB + 64 + lane] = a1;
    }
}

// ---------------------------------------------------------------------------
extern "C" void kernel_launch(void* const* d_in, const int* in_sizes, int n_in,
                              void* d_out, int out_size, void* d_ws, size_t ws_size,
                              hipStream_t stream) {
    const int*   tokens = (const int*)  d_in[0];
    const float* emb    = (const float*)d_in[1];
    const float* w_ih   = (const float*)d_in[2];
    const float* w_hh   = (const float*)d_in[3];
    const float* b_ih   = (const float*)d_in[4];
    const float* b_hh   = (const float*)d_in[5];
    const float* w_out  = (const float*)d_in[6];
    const float* b_out  = (const float*)d_in[7];
    float*       out    = (float*)d_out;

    float* proj = (float*)d_ws;
    float* hbuf = (float*)((char*)d_ws + VOCAB * G4 * sizeof(float));

    build_proj<<<(VOCAB * G4) / 256, 256, 0, stream>>>(emb, w_ih, b_ih, b_hh, proj);

    lstm_rec<<<BATCH, 64, 0, stream>>>(tokens, w_hh, proj, hbuf);

    const int total_pos = BATCH * SEQ;                    // 262144
    const int waves     = total_pos / POS_PER_WAVE;       // 16384
    out_proj<<<waves / 4, 256, 0, stream>>>(hbuf, w_out, b_out, out);
}

// Round 4
// 274.535 us; speedup vs baseline: 1.0271x; 1.0271x over previous
//
#include <hip/hip_runtime.h>

#define VOCAB 128
#define EMB   8
#define HID   32
#define BATCH 512
#define SEQ   512
#define G4    128   // 4*HID
#define KB    8     // recurrence steps per store-flush phase

// ---------------------------------------------------------------------------
// Kernel 1: proj[v][r] = dot(emb[v], w_ih[r]) + b_ih[r] + b_hh[r]
// ---------------------------------------------------------------------------
__global__ void build_proj(const float* __restrict__ emb,
                           const float* __restrict__ w_ih,
                           const float* __restrict__ b_ih,
                           const float* __restrict__ b_hh,
                           float* __restrict__ proj) {
    int idx = blockIdx.x * blockDim.x + threadIdx.x;   // 0 .. 16383
    int v = idx >> 7;
    int r = idx & 127;
    float acc = b_ih[r] + b_hh[r];
#pragma unroll
    for (int e = 0; e < EMB; ++e)
        acc += emb[v * EMB + e] * w_ih[r * EMB + e];
    proj[v * G4 + r] = acc;
}

// ---------------------------------------------------------------------------
// Kernel 2: LSTM recurrence. One wave per batch sequence.
//  - proj table (64 KB) staged in LDS: the steady-state loop has NO global
//    loads at all; xp comes from ds_read (lgkmcnt), stores go out on vmcnt,
//    the two never serialize each other.
//  - weights pinned in VGPRs; amdgpu_waves_per_eu(1,1) grants the full
//    512-VGPR file so the pin lands in registers, not scratch.
//  - lane l owns gate rows l and l+64; h broadcast via v_readlane;
//    gate halves exchanged with v_permlane32_swap_b32.
// ---------------------------------------------------------------------------
__device__ __forceinline__ float sigmoid_fast(float x) {
    return 1.0f / (1.0f + __expf(-x));
}
__device__ __forceinline__ float tanh_fast(float x) {
    return 1.0f - 2.0f / (__expf(2.0f * x) + 1.0f);
}

__global__ __launch_bounds__(64)
__attribute__((amdgpu_waves_per_eu(1, 1)))
void lstm_rec(
    const int*   __restrict__ tokens,   // [B][T]
    const float* __restrict__ w_hh,     // [128][32]
    const float* __restrict__ proj,     // [128][128]
    float*       __restrict__ h_out)    // [B*T][32]
{
    const int b    = blockIdx.x;
    const int lane = threadIdx.x;      // 0..63

    __shared__ float sproj[VOCAB * G4];   // 64 KB

    // ---- stage proj into LDS (once) ----
    {
        const float4* src = (const float4*)proj;
        float4*       dst = (float4*)sproj;
#pragma unroll 4
        for (int i = 0; i < (VOCAB * G4 / 4) / 64; ++i)
            dst[i * 64 + lane] = src[i * 64 + lane];
    }

    // ---- recurrent weights: 2 gate rows per lane, pinned resident ----
    float w0[HID], w1[HID];
#pragma unroll
    for (int j = 0; j < HID; ++j) {
        w0[j] = w_hh[lane * HID + j];
        w1[j] = w_hh[(lane + 64) * HID + j];
    }
#pragma unroll
    for (int j = 0; j < HID; ++j) {
        asm volatile("" : "+v"(w0[j]), "+v"(w1[j]));   // non-rematerializable
    }

    // ---- all 512 tokens of this sequence in lane registers ----
    // lane l holds tok[l*8 .. l*8+7]
    const int* tok = tokens + b * SEQ;
    int tv[KB];
    {
        int4 a = ((const int4*)tok)[lane * 2];
        int4 d = ((const int4*)tok)[lane * 2 + 1];
        tv[0] = a.x; tv[1] = a.y; tv[2] = a.z; tv[3] = a.w;
        tv[4] = d.x; tv[5] = d.y; tv[6] = d.z; tv[7] = d.w;
    }

    __syncthreads();

    float h = 0.0f, c = 0.0f;

    // prime step-0 xp from LDS
    int tk0 = __builtin_amdgcn_readlane(tv[0], 0);
    float xc0 = sproj[tk0 * G4 + lane];
    float xc1 = sproj[tk0 * G4 + 64 + lane];

    float* hp = h_out + (size_t)b * SEQ * HID + lane;   // lanes<32 store
    float hsave[KB];

    for (int t0 = 0; t0 < SEQ; t0 += KB) {
#pragma unroll
        for (int k = 0; k < KB; ++k) {
            // ---- prefetch next step's xp from LDS (1 step ahead) ----
            // position tn = t0+k+1; slot (k+1)&7 is compile-time, lane tn>>3
            const int tn   = (t0 + k + 1) & (SEQ - 1);
            const int tkn  = __builtin_amdgcn_readlane(tv[(k + 1) & 7], tn >> 3);
            float xn0 = sproj[tkn * G4 + lane];
            float xn1 = sproj[tkn * G4 + 64 + lane];

            // ---- matvec: 8 independent chains of depth 8 ----
            float s0 = xc0, s1 = 0.0f, s2 = 0.0f, s3 = 0.0f;  // row lane
            float u0 = xc1, u1 = 0.0f, u2 = 0.0f, u3 = 0.0f;  // row lane+64
            unsigned hb = __float_as_uint(h);
#pragma unroll
            for (int j = 0; j < HID; j += 4) {
                float h0 = __uint_as_float(__builtin_amdgcn_readlane(hb, j));
                float h1 = __uint_as_float(__builtin_amdgcn_readlane(hb, j + 1));
                float h2 = __uint_as_float(__builtin_amdgcn_readlane(hb, j + 2));
                float h3 = __uint_as_float(__builtin_amdgcn_readlane(hb, j + 3));
                s0 = fmaf(h0, w0[j],     s0);
                s1 = fmaf(h1, w0[j + 1], s1);
                s2 = fmaf(h2, w0[j + 2], s2);
                s3 = fmaf(h3, w0[j + 3], s3);
                u0 = fmaf(h0, w1[j],     u0);
                u1 = fmaf(h1, w1[j + 1], u1);
                u2 = fmaf(h2, w1[j + 2], u2);
                u3 = fmaf(h3, w1[j + 3], u3);
            }
            float acc0 = (s0 + s1) + (s2 + s3);  // i (lo lanes) | f (hi lanes)
            float acc1 = (u0 + u1) + (u2 + u3);  // g (lo lanes) | o (hi lanes)

            // broadcast both halves to all lanes via VALU permlane swap
            float iv = acc0, fv = acc0;
            asm("v_permlane32_swap_b32 %0, %1" : "+v"(iv), "+v"(fv));
            float gv = acc1, ov = acc1;
            asm("v_permlane32_swap_b32 %0, %1" : "+v"(gv), "+v"(ov));

            c = sigmoid_fast(fv) * c + sigmoid_fast(iv) * tanh_fast(gv);
            h = sigmoid_fast(ov) * tanh_fast(c);
            hsave[k] = h;

            xc0 = xn0;
            xc1 = xn1;
        }

        // ---- flush h stores; nothing in the loop waits on vmcnt ----
        if (lane < 32) {
#pragma unroll
            for (int k = 0; k < KB; ++k)
                hp[(size_t)(t0 + k) * HID] = hsave[k];
        }
    }
}

// ---------------------------------------------------------------------------
// Kernel 3: logits[pos][v] = h[pos] . w_out[v] + b_out[v]
// ---------------------------------------------------------------------------
#define POS_PER_WAVE 16

__global__ __launch_bounds__(256) void out_proj(
    const float* __restrict__ h,      // [B*T][32]
    const float* __restrict__ w_out,  // [128][32]
    const float* __restrict__ b_out,  // [128]
    float*       __restrict__ out)    // [B*T][128]
{
    const int gtid = blockIdx.x * blockDim.x + threadIdx.x;
    const int wave = gtid >> 6;
    const int lane = threadIdx.x & 63;

    float wv0[HID], wv1[HID];
#pragma unroll
    for (int j = 0; j < HID; ++j) {
        wv0[j] = w_out[lane * HID + j];
        wv1[j] = w_out[(lane + 64) * HID + j];
    }
    const float bb0 = b_out[lane];
    const float bb1 = b_out[lane + 64];

    int pos0 = wave * POS_PER_WAVE;
    for (int p = 0; p < POS_PER_WAVE; ++p) {
        int pos = __builtin_amdgcn_readfirstlane(pos0 + p);
        const float* hp = h + (size_t)pos * HID;
        float a0 = bb0, a1 = bb1;
#pragma unroll
        for (int j4 = 0; j4 < HID / 4; ++j4) {
            float4 hv = *reinterpret_cast<const float4*>(hp + 4 * j4);
            a0 = fmaf(hv.x, wv0[4 * j4 + 0], a0);
            a1 = fmaf(hv.x, wv1[4 * j4 + 0], a1);
            a0 = fmaf(hv.y, wv0[4 * j4 + 1], a0);
            a1 = fmaf(hv.y, wv1[4 * j4 + 1], a1);
            a0 = fmaf(hv.z, wv0[4 * j4 + 2], a0);
            a1 = fmaf(hv.z, wv1[4 * j4 + 2], a1);
            a0 = fmaf(hv.w, wv0[4 * j4 + 3], a0);
            a1 = fmaf(hv.w, wv1[4 * j4 + 3], a1);
        }
        out[(size_t)pos * VOCAB + lane]      = a0;
        out[(size_t)pos * VOCAB + 64 + lane] = a1;
    }
}

// ---------------------------------------------------------------------------
extern "C" void kernel_launch(void* const* d_in, const int* in_sizes, int n_in,
                              void* d_out, int out_size, void* d_ws, size_t ws_size,
                              hipStream_t stream) {
    const int*   tokens = (const int*)  d_in[0];
    const float* emb    = (const float*)d_in[1];
    const float* w_ih   = (const float*)d_in[2];
    const float* w_hh   = (const float*)d_in[3];
    const float* b_ih   = (const float*)d_in[4];
    const float* b_hh   = (const float*)d_in[5];
    const float* w_out  = (const float*)d_in[6];
    const float* b_out  = (const float*)d_in[7];
    float*       out    = (float*)d_out;

    float* proj = (float*)d_ws;
    float* hbuf = (float*)((char*)d_ws + VOCAB * G4 * sizeof(float));

    build_proj<<<(VOCAB * G4) / 256, 256, 0, stream>>>(emb, w_ih, b_ih, b_hh, proj);

    lstm_rec<<<BATCH, 64, 0, stream>>>(tokens, w_hh, proj, hbuf);

    const int total_pos = BATCH * SEQ;                    // 262144
    const int waves     = total_pos / POS_PER_WAVE;       // 16384
    out_proj<<<waves / 4, 256, 0, stream>>>(hbuf, w_out, b_out, out);
}